// Round 7
// baseline (103.608 us; speedup 1.0000x reference)
//
#include <hip/hip_runtime.h>
#include <hip/hip_bf16.h>
#include <stdint.h>

#define B_ 4
#define M_ 4096
#define N_ 4096
#define D_ 256

typedef __attribute__((ext_vector_type(8))) short bf16x8;
typedef __attribute__((ext_vector_type(4))) float f32x4;

// RNE float->bf16 (no NaN in this data)
__device__ inline unsigned short f2bf(float f) {
    unsigned int u = __float_as_uint(f);
    return (unsigned short)((u + 0x7fffu + ((u >> 16) & 1u)) >> 16);
}

// One wave per row: compute 1/||row||, scale, convert to bf16.
__global__ __launch_bounds__(256) void norm_cvt(const float* __restrict__ x,
                                                const float* __restrict__ y,
                                                ushort* __restrict__ xb,
                                                ushort* __restrict__ yb) {
    int gw   = (blockIdx.x * 256 + threadIdx.x) >> 6;
    int lane = threadIdx.x & 63;
    const int R = B_ * 4096;
    const float* src;
    ushort* dst;
    if (gw < R) { src = x + (size_t)gw * D_;        dst = xb + (size_t)gw * D_; }
    else        { src = y + (size_t)(gw - R) * D_;  dst = yb + (size_t)(gw - R) * D_; }

    float4 v = reinterpret_cast<const float4*>(src)[lane];
    float ss = v.x * v.x + v.y * v.y + v.z * v.z + v.w * v.w;
#pragma unroll
    for (int off = 32; off; off >>= 1) ss += __shfl_xor(ss, off);
    float scale = ss > 0.f ? rsqrtf(ss) : 0.f;

    ushort4 o;
    o.x = f2bf(v.x * scale);
    o.y = f2bf(v.y * scale);
    o.z = f2bf(v.z * scale);
    o.w = f2bf(v.w * scale);
    reinterpret_cast<ushort4*>(dst)[lane] = o;
}

// C[b][m][n] = sum_d Yb[b][m][d] * Xb[b][n][d]
// LDS-free, barrier-free GEMM: each wave owns 64 rows x 512 cols.
//  - A panel (64 rows x K=256) lives in registers (32 bf16x8 = 128 VGPR).
//  - B fragments streamed directly from L2 in MFMA layout (no LDS staging).
//  - 8 col-chunks of 64; acc (16 f32x4) reused per chunk; stores overlap
//    the next chunk's loads/compute automatically (no sync points at all).
// XCD locality: bid&7 = XCD; 2 XCDs per batch; per-XCD set A(2MB)+B(1MB) < 4MB L2.
__global__ __launch_bounds__(256, 2) void cosgemm(const ushort* __restrict__ Xb,
                                                  const ushort* __restrict__ Yb,
                                                  float* __restrict__ out) {
    const int w    = threadIdx.x >> 6;
    const int lane = threadIdx.x & 63;
    const int bid  = blockIdx.x;

    const int xcd  = bid & 7;               // XCD round-robin by blockIdx
    const int band = bid >> 3;              // 0..63 : 64-row band
    const int b    = xcd >> 1;              // batch 0..3 (2 XCDs per batch)
    const int cg   = ((xcd & 1) << 2) | w;  // 0..7 : 512-col group
    const int r0   = band << 6;
    const int c0   = cg << 9;

    // per-lane fragment base pointers (row = lane&15, k-slot = lane>>4)
    const ushort* pA = Yb + (((size_t)b * M_ + r0 + (lane & 15)) << 8) + ((lane >> 4) << 3);
    const ushort* pB = Xb + (((size_t)b * N_ + c0 + (lane & 15)) << 8) + ((lane >> 4) << 3);

    // A panel in registers: areg[m][kc] = A[r0+m*16+(lane&15)][kc*32+(lane>>4)*8 ..]
    bf16x8 areg[4][8];
#pragma unroll
    for (int m = 0; m < 4; ++m)
#pragma unroll
        for (int kc = 0; kc < 8; ++kc)
            areg[m][kc] = *reinterpret_cast<const bf16x8*>(pA + m * (16 * D_) + kc * 32);

    const int rj = (lane >> 4) << 2;   // C/D: row = rj + j, col = lane&15  [m89]
    const int cj = lane & 15;

#define LOADB(DST, KC) \
    _Pragma("unroll") for (int n = 0; n < 4; ++n) \
        DST[n] = *reinterpret_cast<const bf16x8*>(pBc + n * (16 * D_) + (KC) * 32);

#define MFMAS(CUR, KC) \
    _Pragma("unroll") for (int m = 0; m < 4; ++m) \
    _Pragma("unroll") for (int n = 0; n < 4; ++n) \
        acc[m][n] = __builtin_amdgcn_mfma_f32_16x16x32_bf16(areg[m][KC], CUR[n], acc[m][n], 0, 0, 0);

#pragma unroll 1
    for (int c = 0; c < 8; ++c) {              // 8 chunks of 64 cols
        const ushort* pBc = pB + (size_t)c * (64 * D_);
        f32x4 acc[4][4];
#pragma unroll
        for (int m = 0; m < 4; ++m)
#pragma unroll
            for (int n = 0; n < 4; ++n)
                acc[m][n] = (f32x4){0.f, 0.f, 0.f, 0.f};

        bf16x8 b0[4], b1[4];
        LOADB(b0, 0)
        // software pipeline, prefetch distance 1, fully static indexing
        LOADB(b1, 1)  MFMAS(b0, 0)
        LOADB(b0, 2)  MFMAS(b1, 1)
        LOADB(b1, 3)  MFMAS(b0, 2)
        LOADB(b0, 4)  MFMAS(b1, 3)
        LOADB(b1, 5)  MFMAS(b0, 4)
        LOADB(b0, 6)  MFMAS(b1, 5)
        LOADB(b1, 7)  MFMAS(b0, 6)
                      MFMAS(b1, 7)

        // store 64x64 chunk; stores drain under next chunk's compute
        const int ccol = c0 + c * 64 + cj;
#pragma unroll
        for (int m = 0; m < 4; ++m) {
#pragma unroll
            for (int j = 0; j < 4; ++j) {
                float* rowp = out + ((size_t)b * M_ + r0 + m * 16 + rj + j) * N_ + ccol;
#pragma unroll
                for (int n = 0; n < 4; ++n)
                    rowp[n * 16] = acc[m][n][j];
            }
        }
    }
#undef LOADB
#undef MFMAS
}

extern "C" void kernel_launch(void* const* d_in, const int* in_sizes, int n_in,
                              void* d_out, int out_size, void* d_ws, size_t ws_size,
                              hipStream_t stream) {
    const float* x = (const float*)d_in[0];   // [4,4096,256] f32
    const float* y = (const float*)d_in[1];   // [4,4096,256] f32
    float* out = (float*)d_out;               // [4,4096,4096] f32

    ushort* xb = (ushort*)d_ws;                       // bf16 normalized x
    ushort* yb = xb + (size_t)B_ * N_ * D_;           // bf16 normalized y

    norm_cvt<<<8192, 256, 0, stream>>>(x, y, xb, yb); // 32768 rows, 4 waves/block
    cosgemm<<<512, 256, 0, stream>>>(xb, yb, out);    // 64 bands x 8 XCD-groups
}

// Round 9
// 77.272 us; speedup vs baseline: 1.3408x; 1.3408x over previous
//
#include <hip/hip_runtime.h>
#include <hip/hip_bf16.h>
#include <stdint.h>

#define B_ 4
#define M_ 4096
#define N_ 4096
#define D_ 256

typedef __attribute__((ext_vector_type(8))) short bf16x8;
typedef __attribute__((ext_vector_type(4))) float f32x4;

#define AS1 __attribute__((address_space(1)))
#define AS3 __attribute__((address_space(3)))

// RNE float->bf16 (no NaN in this data)
__device__ inline unsigned short f2bf(float f) {
    unsigned int u = __float_as_uint(f);
    return (unsigned short)((u + 0x7fffu + ((u >> 16) & 1u)) >> 16);
}

// One wave per row: compute 1/||row||, scale, convert to bf16.
__global__ __launch_bounds__(256) void norm_cvt(const float* __restrict__ x,
                                                const float* __restrict__ y,
                                                ushort* __restrict__ xb,
                                                ushort* __restrict__ yb) {
    int gw   = (blockIdx.x * 256 + threadIdx.x) >> 6;
    int lane = threadIdx.x & 63;
    const int R = B_ * 4096;
    const float* src;
    ushort* dst;
    if (gw < R) { src = x + (size_t)gw * D_;        dst = xb + (size_t)gw * D_; }
    else        { src = y + (size_t)(gw - R) * D_;  dst = yb + (size_t)(gw - R) * D_; }

    float4 v = reinterpret_cast<const float4*>(src)[lane];
    float ss = v.x * v.x + v.y * v.y + v.z * v.z + v.w * v.w;
#pragma unroll
    for (int off = 32; off; off >>= 1) ss += __shfl_xor(ss, off);
    float scale = ss > 0.f ? rsqrtf(ss) : 0.f;

    ushort4 o;
    o.x = f2bf(v.x * scale);
    o.y = f2bf(v.y * scale);
    o.z = f2bf(v.z * scale);
    o.w = f2bf(v.w * scale);
    reinterpret_cast<ushort4*>(dst)[lane] = o;
}

// C[b][m][n] = sum_d Yb[b][m][d] * Xb[b][n][d]
// Block: 128 rows x 4 col-tiles of 128 (quad), 4 waves 2x2 (wave = 64x64).
// A: wave's 64x256 panel in REGISTERS (32 bf16x8; layout validated R6),
//    loaded once from L2 -> zero A LDS traffic, zero A re-staging.
// B: R3/R4-proven path — global_load_lds(16B) + involution swizzle +
//    double-buffered 16KB tiles + counted-vmcnt pipeline. 16 K-steps.
// Stores: 64-store burst at kc==3 per quad (fire-and-forget; R4: burst ok).
__global__ __launch_bounds__(256, 2) void cosgemm(const ushort* __restrict__ Xb,
                                                  const ushort* __restrict__ Yb,
                                                  float* __restrict__ out) {
    // LDS: B double-buffer only: 2 x 16KB
    __shared__ char smem[32768];

    const int tid  = threadIdx.x;
    const int w    = tid >> 6;
    const int lane = tid & 63;

    // XCD-aware bijective swizzle: 1024 blocks, 8 XCDs, 128 per XCD chunk
    int bid = blockIdx.x;
    int swz = ((bid & 7) << 7) | (bid >> 3);
    int b   = swz >> 8;             // batch (0..3)
    int t   = swz & 255;
    int tm  = (t >> 3) << 7;        // 32 row-tiles
    int tn0 = (t & 7) << 9;         // 8 quad-cols * 512

    const ushort* Ag = Yb + ((size_t)b * M_ + tm) * D_;
    const ushort* Bg = Xb + ((size_t)b * N_ + tn0) * D_;

    const int wr = (w >> 1) << 6;   // wave's 64-row block
    const int wc = (w & 1) << 6;    // wave's 64-col block

    // ---- A panel into registers (issue first; drained by the s=0 gate).
    // MFMA A layout (R6-validated): lane holds A[row=lane&15][k=(lane>>4)*8..+7]
    const ushort* pA = Ag + (size_t)(wr + (lane & 15)) * D_ + ((lane >> 4) << 3);
    bf16x8 areg[4][8];
#pragma unroll
    for (int m = 0; m < 4; ++m)
#pragma unroll
        for (int k8 = 0; k8 < 8; ++k8)
            areg[m][k8] = *reinterpret_cast<const bf16x8*>(pA + m * (16 * D_) + k8 * 32);

    // ---- B staging: chunk c = 8 B-rows (128B each); linear LDS dest,
    // inverse-swizzled source: LDS slot s of row r holds global slot s^(r&7).
    const int srow  = lane >> 3;
    const int gslot = (lane & 7) ^ srow;
    auto stageB = [&](int buf, int ct, int kc) {
        char* base = smem + buf * 16384;
        const ushort* Bq = Bg + (size_t)(ct * 128) * D_ + kc * 64;
#pragma unroll
        for (int i = 0; i < 4; ++i) {
            int c = i * 4 + w;                           // 16 chunks of 1KB
            const ushort* gb = Bq + (size_t)(c * 8 + srow) * D_ + gslot * 8;
            __builtin_amdgcn_global_load_lds((const AS1 void*)gb,
                                             (AS3 void*)(base + c * 1024), 16, 0, 0);
        }
    };

    // C/D layout: col = lane&15, row = (lane>>4)*4 + reg   [m89-verified]
    const int rj = (lane >> 4) << 2;
    const int cj = lane & 15;

    f32x4 acc[4][4];

    stageB(0, 0, 0);    // queue: [A 32, stage0 4]

#pragma unroll
    for (int s = 0; s < 16; ++s) {
        const int ct = s >> 2, kc = s & 3, buf = s & 1;
        // barrier 1: all waves done reading buf^1 -> safe to overwrite
        __builtin_amdgcn_s_barrier();
        if (s < 15) stageB(buf ^ 1, (s + 1) >> 2, (s + 1) & 3);
        // Counted drain of stage(s) (s=0: plus the A-register loads).
        // Steady queues: s%4==0,s>=4: [stage(s)4, stores64, stage(s+1)4] = 72
        //   -> vmcnt(63) drains stage(s)+5 stores (HW max 63; extra drain safe)
        // else: [storesR?, stage(s)4, stage(s+1)4] -> vmcnt(4)
        // s==15: no stage(16) -> full drain
        if (s == 15)                 asm volatile("s_waitcnt vmcnt(0)"  ::: "memory");
        else if (s >= 4 && kc == 0)  asm volatile("s_waitcnt vmcnt(63)" ::: "memory");
        else                         asm volatile("s_waitcnt vmcnt(4)"  ::: "memory");
        // barrier 2: buf[s] ready for every wave
        __builtin_amdgcn_s_barrier();
        __builtin_amdgcn_sched_barrier(0);

        const char* Bbase = smem + buf * 16384;
        if (kc == 0) {
#pragma unroll
            for (int m = 0; m < 4; ++m)
#pragma unroll
                for (int n = 0; n < 4; ++n)
                    acc[m][n] = (f32x4){0.f, 0.f, 0.f, 0.f};
        }
#pragma unroll
        for (int ks = 0; ks < 2; ++ks) {
            const int colb = ((ks * 4 + (lane >> 4)) ^ (lane & 7)) << 4;
            bf16x8 bfr[4];
#pragma unroll
            for (int n = 0; n < 4; ++n) {
                int row = wc + n * 16 + (lane & 15);
                bfr[n] = *reinterpret_cast<const bf16x8*>(Bbase + row * 128 + colb);
            }
#pragma unroll
            for (int m = 0; m < 4; ++m)
#pragma unroll
                for (int n = 0; n < 4; ++n)
                    acc[m][n] = __builtin_amdgcn_mfma_f32_16x16x32_bf16(
                        areg[m][kc * 2 + ks], bfr[n], acc[m][n], 0, 0, 0);
        }

        // quad finished: burst-store wave's 64x64 chunk (64 stores),
        // fire-and-forget; drained transitively by later gates.
        if (kc == 3) {
            const int tn = tn0 + ct * 128;
#pragma unroll
            for (int m = 0; m < 4; ++m) {
#pragma unroll
                for (int j = 0; j < 4; ++j) {
                    size_t r = (size_t)(tm + wr + m * 16 + rj + j);
                    float* rowp = out + ((size_t)b * M_ + r) * N_ + tn + wc + cj;
#pragma unroll
                    for (int n = 0; n < 4; ++n)
                        rowp[n * 16] = acc[m][n][j];
                }
            }
        }
    }
}

extern "C" void kernel_launch(void* const* d_in, const int* in_sizes, int n_in,
                              void* d_out, int out_size, void* d_ws, size_t ws_size,
                              hipStream_t stream) {
    const float* x = (const float*)d_in[0];   // [4,4096,256] f32
    const float* y = (const float*)d_in[1];   // [4,4096,256] f32
    float* out = (float*)d_out;               // [4,4096,4096] f32

    ushort* xb = (ushort*)d_ws;                       // bf16 normalized x
    ushort* yb = xb + (size_t)B_ * N_ * D_;           // bf16 normalized y

    norm_cvt<<<8192, 256, 0, stream>>>(x, y, xb, yb); // 32768 rows, 4 waves/block
    cosgemm<<<1024, 256, 0, stream>>>(xb, yb, out);   // 4 batches * 32 * 8 quad-tiles
}